// Round 11
// baseline (146.664 us; speedup 1.0000x reference)
//
#include <hip/hip_runtime.h>

#define N_NODES 50000
#define N_EDGES 600000
#define DIM 128
#define NCLS 10
#define ELLW 64                 // max degree (mean 12; P(>64) ~ e^-64)
#define NBUCK 391               // buckets of 128 nodes: bucket = dst >> 7
#define SUBC 8                  // sub-cursors per bucket (contention ~192 each)
#define CAP 384                 // slots per (bucket,sub): mean 192, +10 sigma
#define CPAD 16                 // counter stride (64B line)
#define EPSF 1e-15f
#define MAXNORM 0.99999f  // 1 - 1e-5
#define NTILE ((N_NODES + 63) / 64)   // 782
#define FILL_BLOCKS 586               // ceil(600000 / (256*4))
#define XFORM_BLOCKS 512

typedef __attribute__((ext_vector_type(8))) short bf16x8;
typedef __attribute__((ext_vector_type(4))) float f32x4;

__device__ inline float waveSum(float v) {
#pragma unroll
  for (int o = 1; o < 64; o <<= 1) v += __shfl_xor(v, o, 64);
  return v;
}

__device__ inline unsigned short f2bf(float f) {
  union { float f; unsigned u; } c; c.f = f;
  return (unsigned short)((c.u + 0x7FFFu + ((c.u >> 16) & 1u)) >> 16);
}
__device__ inline float bf_lo(unsigned u) {
  union { unsigned u; float f; } c; c.u = u << 16; return c.f;
}
__device__ inline float bf_hi(unsigned u) {
  union { unsigned u; float f; } c; c.u = u & 0xFFFF0000u; return c.f;
}

// ---------------- init: zero bucket cursors + convert W1/W2 to bf16 ----------------
__global__ __launch_bounds__(256) void init_kernel(
    int* __restrict__ bcur, const float* __restrict__ W1, const float* __restrict__ W2,
    unsigned short* __restrict__ W1b, unsigned short* __restrict__ W2b)
{
  int i = blockIdx.x * 256 + threadIdx.x;
  if (i < NBUCK * SUBC * CPAD) bcur[i] = 0;
  if (i < DIM * DIM) {
    W1b[i] = f2bf(W1[i]);
    W2b[i] = f2bf(W2[i]);
  }
}

// ---------------- fused: edge binning pass 1 + layer-1 transform ----------------
__global__ __launch_bounds__(256, 2) void fill_transform(
    const int* __restrict__ src, const int* __restrict__ dst,
    int* __restrict__ bcur, unsigned* __restrict__ interm,
    const float* __restrict__ x, const unsigned short* __restrict__ Wb,
    const float* __restrict__ b, unsigned short* __restrict__ y)
{
  __shared__ __align__(16) unsigned short At[64 * DIM];  // swizzled bf16 t-tile

  if (blockIdx.x < FILL_BLOCKS) {
    const int nthr = FILL_BLOCKS * 256;
    const int e = blockIdx.x * 256 + threadIdx.x;
    const int q = threadIdx.x & (SUBC - 1);
    const int e0 = e, e1 = e + nthr, e2 = e + 2 * nthr, e3 = e + 3 * nthr;
    int d0, d1, d2, d3, s0, s1, s2, s3;
    if (e0 < N_EDGES) { d0 = dst[e0]; s0 = src[e0]; }
    if (e1 < N_EDGES) { d1 = dst[e1]; s1 = src[e1]; }
    if (e2 < N_EDGES) { d2 = dst[e2]; s2 = src[e2]; }
    if (e3 < N_EDGES) { d3 = dst[e3]; s3 = src[e3]; }
    int p0, p1, p2, p3;
    if (e0 < N_EDGES) p0 = atomicAdd(&bcur[((d0 >> 7) * SUBC + q) * CPAD], 1);
    if (e1 < N_EDGES) p1 = atomicAdd(&bcur[((d1 >> 7) * SUBC + q) * CPAD], 1);
    if (e2 < N_EDGES) p2 = atomicAdd(&bcur[((d2 >> 7) * SUBC + q) * CPAD], 1);
    if (e3 < N_EDGES) p3 = atomicAdd(&bcur[((d3 >> 7) * SUBC + q) * CPAD], 1);
    if (e0 < N_EDGES) interm[(size_t)((d0 >> 7) * SUBC + q) * CAP + p0] = ((unsigned)(d0 & 127) << 16) | (unsigned)s0;
    if (e1 < N_EDGES) interm[(size_t)((d1 >> 7) * SUBC + q) * CAP + p1] = ((unsigned)(d1 & 127) << 16) | (unsigned)s1;
    if (e2 < N_EDGES) interm[(size_t)((d2 >> 7) * SUBC + q) * CAP + p2] = ((unsigned)(d2 & 127) << 16) | (unsigned)s2;
    if (e3 < N_EDGES) interm[(size_t)((d3 >> 7) * SUBC + q) * CAP + p3] = ((unsigned)(d3 & 127) << 16) | (unsigned)s3;
    return;
  }

  // ---------------- transform path (layer 1: f32 manifold in) ----------------
  const int tid = threadIdx.x;
  const int w = tid >> 6;
  const int l = tid & 63;
  const int lr = l & 15;
  const int lg = l >> 4;

  bf16x8 bf[8][4];
#pragma unroll
  for (int n = 0; n < 8; ++n)
#pragma unroll
    for (int kc = 0; kc < 4; ++kc)
      bf[n][kc] = *(const bf16x8*)(Wb + (n * 16 + lr) * DIM + kc * 32 + lg * 8);

  float bias[8];
#pragma unroll
  for (int n = 0; n < 8; ++n) bias[n] = b[n * 16 + lr];

  const int row = w * 16 + lr;

  for (int tile = blockIdx.x - FILL_BLOCKS; tile < NTILE; tile += XFORM_BLOCKS) {
    const int base = tile * 64;
    const int node = base + row;
    __syncthreads();

    float v[32];
    if (node < N_NODES) {
      const float4* xr = (const float4*)(x + (size_t)node * DIM + lg * 32);
#pragma unroll
      for (int q = 0; q < 8; ++q) {
        float4 f = xr[q];
        v[q * 4 + 0] = f.x; v[q * 4 + 1] = f.y; v[q * 4 + 2] = f.z; v[q * 4 + 3] = f.w;
      }
    } else {
#pragma unroll
      for (int q = 0; q < 32; ++q) v[q] = 0.f;
    }
    float sq = 0.f;
#pragma unroll
    for (int q = 0; q < 32; ++q) sq += v[q] * v[q];
    sq += __shfl_xor(sq, 16, 64);
    sq += __shfl_xor(sq, 32, 64);
    float n1 = sqrtf(sq);
    float nc = fmaxf(n1, EPSF);
    float nm = fminf(nc, MAXNORM);
    float scale = 0.5f * logf((1.f + nm) / (1.f - nm)) / nc;
#pragma unroll
    for (int s = 0; s < 4; ++s) {
      unsigned short tmp[8];
#pragma unroll
      for (int e = 0; e < 8; ++e) tmp[e] = f2bf(v[s * 8 + e] * scale);
      int byte = row * 256 + lg * 64 + s * 16;
      byte ^= (row & 7) << 4;
      *(bf16x8*)((char*)At + byte) = *(const bf16x8*)tmp;
    }
    __syncthreads();

    f32x4 acc[8];
#pragma unroll
    for (int n = 0; n < 8; ++n) {
      acc[n][0] = bias[n]; acc[n][1] = bias[n]; acc[n][2] = bias[n]; acc[n][3] = bias[n];
    }
#pragma unroll
    for (int kc = 0; kc < 4; ++kc) {
      int arow = w * 16 + lr;
      int byte = arow * 256 + kc * 64 + lg * 16;
      byte ^= (arow & 7) << 4;
      bf16x8 af = *(const bf16x8*)((const char*)At + byte);
#pragma unroll
      for (int n = 0; n < 8; ++n)
        acc[n] = __builtin_amdgcn_mfma_f32_16x16x32_bf16(af, bf[n][kc], acc[n], 0, 0, 0);
    }

    float rs[4];
#pragma unroll
    for (int j = 0; j < 4; ++j) {
      float s2 = 0.f;
#pragma unroll
      for (int n = 0; n < 8; ++n) s2 += acc[n][j] * acc[n][j];
      s2 += __shfl_xor(s2, 1, 64);
      s2 += __shfl_xor(s2, 2, 64);
      s2 += __shfl_xor(s2, 4, 64);
      s2 += __shfl_xor(s2, 8, 64);
      float n2 = sqrtf(s2);
      float n2c = fmaxf(n2, EPSF);
      rs[j] = tanhf(n2c) / n2c;
    }
#pragma unroll
    for (int j = 0; j < 4; ++j) {
      int nrow = base + w * 16 + lg * 4 + j;
      if (nrow < N_NODES) {
        unsigned short* yr = y + (size_t)nrow * DIM + lr;
#pragma unroll
        for (int n = 0; n < 8; ++n) yr[n * 16] = f2bf(acc[n][j] * rs[j]);
      }
    }
  }
}

// ---------------- pass 2: bucket -> LDS ELL tile -> coalesced global write -------
__global__ __launch_bounds__(256) void binfill_kernel(
    const unsigned* __restrict__ interm, const int* __restrict__ bcur,
    int* __restrict__ ell, int* __restrict__ deg)
{
  __shared__ int tile[128 * ELLW];   // 32 KB
  __shared__ int lcur[128];
  const int b = blockIdx.x;
  const int tid = threadIdx.x;
  if (tid < 128) lcur[tid] = 0;
  __syncthreads();
#pragma unroll
  for (int q = 0; q < SUBC; ++q) {
    int c = bcur[(b * SUBC + q) * CPAD];
    c = min(c, CAP);
    const unsigned* seg = interm + (size_t)(b * SUBC + q) * CAP;
    for (int i = tid; i < c; i += 256) {
      unsigned u = seg[i];
      int d = u >> 16, s = (int)(u & 0xFFFFu);
      int slot = atomicAdd(&lcur[d], 1);
      tile[d * ELLW + slot] = s;
    }
  }
  __syncthreads();
  int4* dstp = (int4*)(ell + (size_t)b * 128 * ELLW);
  const int4* srcp = (const int4*)tile;
#pragma unroll
  for (int k = 0; k < 8; ++k) dstp[tid + k * 256] = srcp[tid + k * 256];
  if (tid < 128) {
    int node = b * 128 + tid;
    if (node < N_NODES) deg[node] = lcur[tid];
  }
}

// ---------------- gather + relu + logmap0 -> bf16 tangent ----------------
__global__ __launch_bounds__(256) void gatherT_kernel(
    const unsigned short* __restrict__ y, const int* __restrict__ deg,
    const int* __restrict__ ell, unsigned short* __restrict__ tout)
{
  const int node = blockIdx.x * 4 + (threadIdx.x >> 6);
  if (node >= N_NODES) return;
  const int lane = threadIdx.x & 63;
  const int* lst = ell + (size_t)node * ELLW;
  const int cnt = deg[node];
  float2 a0 = {0.f, 0.f}, a1 = {0.f, 0.f}, a2 = {0.f, 0.f}, a3 = {0.f, 0.f};
  int j = 0;
  for (; j + 7 < cnt; j += 8) {
    unsigned u0 = ((const unsigned*)(y + (size_t)lst[j    ] * DIM))[lane];
    unsigned u1 = ((const unsigned*)(y + (size_t)lst[j + 1] * DIM))[lane];
    unsigned u2 = ((const unsigned*)(y + (size_t)lst[j + 2] * DIM))[lane];
    unsigned u3 = ((const unsigned*)(y + (size_t)lst[j + 3] * DIM))[lane];
    unsigned u4 = ((const unsigned*)(y + (size_t)lst[j + 4] * DIM))[lane];
    unsigned u5 = ((const unsigned*)(y + (size_t)lst[j + 5] * DIM))[lane];
    unsigned u6 = ((const unsigned*)(y + (size_t)lst[j + 6] * DIM))[lane];
    unsigned u7 = ((const unsigned*)(y + (size_t)lst[j + 7] * DIM))[lane];
    a0.x += bf_lo(u0); a0.y += bf_hi(u0);
    a1.x += bf_lo(u1); a1.y += bf_hi(u1);
    a2.x += bf_lo(u2); a2.y += bf_hi(u2);
    a3.x += bf_lo(u3); a3.y += bf_hi(u3);
    a0.x += bf_lo(u4); a0.y += bf_hi(u4);
    a1.x += bf_lo(u5); a1.y += bf_hi(u5);
    a2.x += bf_lo(u6); a2.y += bf_hi(u6);
    a3.x += bf_lo(u7); a3.y += bf_hi(u7);
  }
  for (; j + 3 < cnt; j += 4) {
    unsigned u0 = ((const unsigned*)(y + (size_t)lst[j    ] * DIM))[lane];
    unsigned u1 = ((const unsigned*)(y + (size_t)lst[j + 1] * DIM))[lane];
    unsigned u2 = ((const unsigned*)(y + (size_t)lst[j + 2] * DIM))[lane];
    unsigned u3 = ((const unsigned*)(y + (size_t)lst[j + 3] * DIM))[lane];
    a0.x += bf_lo(u0); a0.y += bf_hi(u0);
    a1.x += bf_lo(u1); a1.y += bf_hi(u1);
    a2.x += bf_lo(u2); a2.y += bf_hi(u2);
    a3.x += bf_lo(u3); a3.y += bf_hi(u3);
  }
  for (; j < cnt; ++j) {
    unsigned u0 = ((const unsigned*)(y + (size_t)lst[j] * DIM))[lane];
    a0.x += bf_lo(u0); a0.y += bf_hi(u0);
  }
  float2 r;
  r.x = fmaxf((a0.x + a1.x) + (a2.x + a3.x), 0.f);  // relu
  r.y = fmaxf((a0.y + a1.y) + (a2.y + a3.y), 0.f);

  float s = waveSum(r.x * r.x + r.y * r.y);
  float n = sqrtf(s);
  float nc = fmaxf(n, EPSF);
  float nm = fminf(nc, MAXNORM);
  float scale = 0.5f * logf((1.0f + nm) / (1.0f - nm)) / nc;
  unsigned u = (unsigned)f2bf(r.x * scale) | ((unsigned)f2bf(r.y * scale) << 16);
  ((unsigned*)(tout + (size_t)node * DIM))[lane] = u;
}

// ---------------- layer-2 transform: bf16 tangent in -> (W t + b) -> expmap0 ------
__global__ __launch_bounds__(256, 2) void transform2_mfma(
    const unsigned short* __restrict__ t, const unsigned short* __restrict__ Wb,
    const float* __restrict__ b, unsigned short* __restrict__ y)
{
  const int tid = threadIdx.x;
  const int w = tid >> 6;
  const int l = tid & 63;
  const int lr = l & 15;
  const int lg = l >> 4;

  __shared__ __align__(16) unsigned short At[64 * DIM];

  bf16x8 bf[8][4];
#pragma unroll
  for (int n = 0; n < 8; ++n)
#pragma unroll
    for (int kc = 0; kc < 4; ++kc)
      bf[n][kc] = *(const bf16x8*)(Wb + (n * 16 + lr) * DIM + kc * 32 + lg * 8);

  float bias[8];
#pragma unroll
  for (int n = 0; n < 8; ++n) bias[n] = b[n * 16 + lr];

  const int row = w * 16 + lr;

  for (int tile = blockIdx.x; tile < NTILE; tile += gridDim.x) {
    const int base = tile * 64;
    const int node = base + row;
    __syncthreads();

#pragma unroll
    for (int s = 0; s < 4; ++s) {
      bf16x8 frag;
      if (node < N_NODES)
        frag = *(const bf16x8*)(t + (size_t)node * DIM + lg * 32 + s * 8);
      else
        frag = bf16x8{0, 0, 0, 0, 0, 0, 0, 0};
      int byte = row * 256 + lg * 64 + s * 16;
      byte ^= (row & 7) << 4;
      *(bf16x8*)((char*)At + byte) = frag;
    }
    __syncthreads();

    f32x4 acc[8];
#pragma unroll
    for (int n = 0; n < 8; ++n) {
      acc[n][0] = bias[n]; acc[n][1] = bias[n]; acc[n][2] = bias[n]; acc[n][3] = bias[n];
    }
#pragma unroll
    for (int kc = 0; kc < 4; ++kc) {
      int arow = w * 16 + lr;
      int byte = arow * 256 + kc * 64 + lg * 16;
      byte ^= (arow & 7) << 4;
      bf16x8 af = *(const bf16x8*)((const char*)At + byte);
#pragma unroll
      for (int n = 0; n < 8; ++n)
        acc[n] = __builtin_amdgcn_mfma_f32_16x16x32_bf16(af, bf[n][kc], acc[n], 0, 0, 0);
    }

    float rs[4];
#pragma unroll
    for (int j = 0; j < 4; ++j) {
      float s2 = 0.f;
#pragma unroll
      for (int n = 0; n < 8; ++n) s2 += acc[n][j] * acc[n][j];
      s2 += __shfl_xor(s2, 1, 64);
      s2 += __shfl_xor(s2, 2, 64);
      s2 += __shfl_xor(s2, 4, 64);
      s2 += __shfl_xor(s2, 8, 64);
      float n2 = sqrtf(s2);
      float n2c = fmaxf(n2, EPSF);
      rs[j] = tanhf(n2c) / n2c;
    }
#pragma unroll
    for (int j = 0; j < 4; ++j) {
      int nrow = base + w * 16 + lg * 4 + j;
      if (nrow < N_NODES) {
        unsigned short* yr = y + (size_t)nrow * DIM + lr;
#pragma unroll
        for (int n = 0; n < 8; ++n) yr[n * 16] = f2bf(acc[n][j] * rs[j]);
      }
    }
  }
}

// ---------------- classifier head: out = t2 @ Wc^T + bc via MFMA ----------------
__global__ __launch_bounds__(256) void head_mfma(
    const unsigned short* __restrict__ t2, const float* __restrict__ Wc,
    const float* __restrict__ bc, float* __restrict__ out)
{
  const int base = blockIdx.x * 64;
  const int w = threadIdx.x >> 6;
  const int l = threadIdx.x & 63;
  const int lr = l & 15;
  const int lg = l >> 4;

  bf16x8 bw[4];
#pragma unroll
  for (int kc = 0; kc < 4; ++kc) {
    unsigned short tmp[8];
    if (lr < NCLS) {
      const float* wr = Wc + (size_t)lr * DIM + kc * 32 + lg * 8;
#pragma unroll
      for (int e = 0; e < 8; ++e) tmp[e] = f2bf(wr[e]);
    } else {
#pragma unroll
      for (int e = 0; e < 8; ++e) tmp[e] = 0;
    }
    bw[kc] = *(const bf16x8*)tmp;
  }
  const float bias = (lr < NCLS) ? bc[lr] : 0.f;

  const int arow = base + w * 16 + lr;
  f32x4 acc;
  acc[0] = bias; acc[1] = bias; acc[2] = bias; acc[3] = bias;
#pragma unroll
  for (int kc = 0; kc < 4; ++kc) {
    bf16x8 af;
    if (arow < N_NODES)
      af = *(const bf16x8*)(t2 + (size_t)arow * DIM + kc * 32 + lg * 8);
    else
      af = bf16x8{0, 0, 0, 0, 0, 0, 0, 0};
    acc = __builtin_amdgcn_mfma_f32_16x16x32_bf16(af, bw[kc], acc, 0, 0, 0);
  }

  if (lr < NCLS) {
#pragma unroll
    for (int j = 0; j < 4; ++j) {
      int nrow = base + w * 16 + lg * 4 + j;
      if (nrow < N_NODES) out[(size_t)nrow * NCLS + lr] = acc[j];
    }
  }
}

extern "C" void kernel_launch(void* const* d_in, const int* in_sizes, int n_in,
                              void* d_out, int out_size, void* d_ws, size_t ws_size,
                              hipStream_t stream)
{
  const int* edge = (const int*)d_in[0];
  const int* src = edge;            // edge_index[0]
  const int* dst = edge + N_EDGES;  // edge_index[1]
  const float* x  = (const float*)d_in[1];
  const float* W1 = (const float*)d_in[2];
  const float* b1 = (const float*)d_in[3];
  const float* W2 = (const float*)d_in[4];
  const float* b2 = (const float*)d_in[5];
  const float* Wc = (const float*)d_in[6];
  const float* bc = (const float*)d_in[7];
  float* out = (float*)d_out;

  unsigned short* ybuf = (unsigned short*)d_ws;          // bf16 y [N, D]
  unsigned short* tbuf = ybuf + (size_t)N_NODES * DIM;   // bf16 tangent [N, D]
  unsigned short* W1b = tbuf + (size_t)N_NODES * DIM;
  unsigned short* W2b = W1b + DIM * DIM;
  int* bcur = (int*)(W2b + DIM * DIM);                   // NBUCK*SUBC*CPAD
  unsigned* interm = (unsigned*)(bcur + NBUCK * SUBC * CPAD);  // NBUCK*SUBC*CAP
  int* ell = (int*)(interm + (size_t)NBUCK * SUBC * CAP);      // NBUCK*128*ELLW
  int* deg = ell + (size_t)NBUCK * 128 * ELLW;                 // N_NODES

  // --- init (zero bucket cursors) + W->bf16 ---
  init_kernel<<<(N_NODES + 255) / 256, 256, 0, stream>>>(bcur, W1, W2, W1b, W2b);

  // --- pass 1 (edge binning) fused with layer-1 transform ---
  fill_transform<<<FILL_BLOCKS + XFORM_BLOCKS, 256, 0, stream>>>(
      src, dst, bcur, interm, x, W1b, b1, ybuf);

  // --- pass 2: bucket -> ELL (coalesced) + degrees ---
  binfill_kernel<<<NBUCK, 256, 0, stream>>>(interm, bcur, ell, deg);

  // --- gather + relu + logmap -> t (bf16) ---
  gatherT_kernel<<<(N_NODES + 3) / 4, 256, 0, stream>>>(ybuf, deg, ell, tbuf);

  // --- Layer 2: t (bf16 tangent) -> y2 (bf16) ---
  transform2_mfma<<<512, 256, 0, stream>>>(tbuf, W2b, b2, ybuf);

  // --- gather + relu + logmap -> t2 (bf16) ---
  gatherT_kernel<<<(N_NODES + 3) / 4, 256, 0, stream>>>(ybuf, deg, ell, tbuf);

  // --- classifier head ---
  head_mfma<<<NTILE, 256, 0, stream>>>(tbuf, Wc, bc, out);
}